// Round 4
// baseline (639.900 us; speedup 1.0000x reference)
//
#include <hip/hip_runtime.h>

#define N_NODES 50000
#define N_EDGES 800000
#define FDIM 64
#define NST 50000  // PT row stride (floats)

// ---------------- edge weight + CSR construction ----------------

__global__ __launch_bounds__(256) void hist_kernel(const int* __restrict__ row,
                                                   int* __restrict__ cnt, int E) {
  int e = blockIdx.x * 256 + threadIdx.x;
  if (e < E) atomicAdd(&cnt[row[e]], 1);
}

__global__ __launch_bounds__(1024) void prefix_kernel(int* __restrict__ cnt,
                                                      int* __restrict__ offs,
                                                      int n, int E) {
  __shared__ int tot[1024];
  int t = threadIdx.x;
  int CH = (n + 1023) >> 10;
  int b = t * CH;
  int e = min(b + CH, n);
  int s = 0;
  for (int i = b; i < e; ++i) s += cnt[i];
  tot[t] = s;
  __syncthreads();
  for (int d = 1; d < 1024; d <<= 1) {
    int add = (t >= d) ? tot[t - d] : 0;
    __syncthreads();
    tot[t] += add;
    __syncthreads();
  }
  int run = (t == 0) ? 0 : tot[t - 1];
  for (int i = b; i < e; ++i) {
    int h = cnt[i];
    offs[i] = run;
    cnt[i] = run;  // becomes the scatter cursor
    run += h;
  }
  if (t == 0) offs[n] = E;
}

__global__ __launch_bounds__(256) void scatter_kernel(
    const int* __restrict__ row, const int* __restrict__ col,
    const float* __restrict__ ent, const float* __restrict__ ccf,
    const float* __restrict__ wsym, const float* __restrict__ encw,
    const float* __restrict__ encb, const float* __restrict__ q,
    int* __restrict__ cursor, int* __restrict__ col_s,
    float2* __restrict__ ws, int E) {
  int e = blockIdx.x * 256 + threadIdx.x;
  if (e >= E) return;
  float se = encw[0] * ent[e] + encw[1] * ccf[e] + encb[0];
  float ph = q[0] * se;
  float sw, cw;
  sincosf(ph, &sw, &cw);
  float w = wsym[e];
  int pos = atomicAdd(&cursor[row[e]], 1);
  col_s[pos] = col[e];
  ws[pos] = make_float2(w * cw, w * sw);
}

// ---------------- weight transpose prep ----------------

__global__ __launch_bounds__(256) void prep_weights(
    const float* __restrict__ r0, const float* __restrict__ i0,
    const float* __restrict__ r1, const float* __restrict__ i1,
    float* __restrict__ r0T, float* __restrict__ i0T, float* __restrict__ r1T,
    float* __restrict__ i1T) {
  int t = blockIdx.x * 256 + threadIdx.x;
  if (t < 128 * 64) {  // [128 h][64 f] -> [64 f][128 h]
    int h = t / 64, f = t % 64;
    r0T[f * 128 + h] = r0[t];
    i0T[f * 128 + h] = i0[t];
  }
  if (t < 128 * 128) {  // [128 h][128 f] -> [128 f][128 h]
    int h = t / 128, f = t % 128;
    r1T[f * 128 + h] = r1[t];
    i1T[f * 128 + h] = i1[t];
  }
}

// ---------------- pack re/im into interleaved rows ----------------

__global__ __launch_bounds__(256) void pack_kernel(const float* __restrict__ re,
                                                   const float* __restrict__ im,
                                                   float2* __restrict__ X,
                                                   int total) {  // total = N*64
  int i = blockIdx.x * 256 + threadIdx.x;
  if (i < total) X[i] = make_float2(re[i], im[i]);
}

// ---------------- complex propagation: up to 8 edges in flight ----------------
// X rows are [re0,im0,re1,im1,...] (128 floats). Lane l: half = l>>5 picks
// edge j+2k+half; l&31 picks a float4 (2 features re+im). shfl_xor(32) combines.

__global__ __launch_bounds__(256) void prop_kernel(
    const float* __restrict__ X, float* __restrict__ Y,
    const int* __restrict__ offs, const int* __restrict__ col_s,
    const float2* __restrict__ ws, int n) {
  int wave = (int)((blockIdx.x * (size_t)blockDim.x + threadIdx.x) >> 6);
  int lane = threadIdx.x & 63;
  if (wave >= n) return;
  int half = lane >> 5, l5 = lane & 31;
  const float* Xl = X + l5 * 4;
  int beg = offs[wave], end = offs[wave + 1];
  float4 acc = make_float4(0.f, 0.f, 0.f, 0.f);
  int j = beg;
  for (; j + 8 <= end; j += 8) {
    int c0 = col_s[j + half];
    int c1 = col_s[j + 2 + half];
    int c2 = col_s[j + 4 + half];
    int c3 = col_s[j + 6 + half];
    float2 w0 = ws[j + half];
    float2 w1 = ws[j + 2 + half];
    float2 w2 = ws[j + 4 + half];
    float2 w3 = ws[j + 6 + half];
    float4 x0 = *(const float4*)&Xl[(size_t)c0 * 128];
    float4 x1 = *(const float4*)&Xl[(size_t)c1 * 128];
    float4 x2 = *(const float4*)&Xl[(size_t)c2 * 128];
    float4 x3 = *(const float4*)&Xl[(size_t)c3 * 128];
    acc.x += w0.x * x0.x - w0.y * x0.y;
    acc.y += w0.y * x0.x + w0.x * x0.y;
    acc.z += w0.x * x0.z - w0.y * x0.w;
    acc.w += w0.y * x0.z + w0.x * x0.w;
    acc.x += w1.x * x1.x - w1.y * x1.y;
    acc.y += w1.y * x1.x + w1.x * x1.y;
    acc.z += w1.x * x1.z - w1.y * x1.w;
    acc.w += w1.y * x1.z + w1.x * x1.w;
    acc.x += w2.x * x2.x - w2.y * x2.y;
    acc.y += w2.y * x2.x + w2.x * x2.y;
    acc.z += w2.x * x2.z - w2.y * x2.w;
    acc.w += w2.y * x2.z + w2.x * x2.w;
    acc.x += w3.x * x3.x - w3.y * x3.y;
    acc.y += w3.y * x3.x + w3.x * x3.y;
    acc.z += w3.x * x3.z - w3.y * x3.w;
    acc.w += w3.y * x3.z + w3.x * x3.w;
  }
  for (; j + 4 <= end; j += 4) {
    int c0 = col_s[j + half];
    int c1 = col_s[j + 2 + half];
    float2 w0 = ws[j + half];
    float2 w1 = ws[j + 2 + half];
    float4 x0 = *(const float4*)&Xl[(size_t)c0 * 128];
    float4 x1 = *(const float4*)&Xl[(size_t)c1 * 128];
    acc.x += w0.x * x0.x - w0.y * x0.y;
    acc.y += w0.y * x0.x + w0.x * x0.y;
    acc.z += w0.x * x0.z - w0.y * x0.w;
    acc.w += w0.y * x0.z + w0.x * x0.w;
    acc.x += w1.x * x1.x - w1.y * x1.y;
    acc.y += w1.y * x1.x + w1.x * x1.y;
    acc.z += w1.x * x1.z - w1.y * x1.w;
    acc.w += w1.y * x1.z + w1.x * x1.w;
  }
  for (; j < end; j += 2) {
    int je = j + half;
    bool valid = je < end;
    int jc = valid ? je : beg;
    float2 w = ws[jc];
    float wr = valid ? w.x : 0.f;
    float wi = valid ? w.y : 0.f;
    int cc = col_s[jc];
    float4 x = *(const float4*)&Xl[(size_t)cc * 128];
    acc.x += wr * x.x - wi * x.y;
    acc.y += wi * x.x + wr * x.y;
    acc.z += wr * x.z - wi * x.w;
    acc.w += wi * x.z + wr * x.w;
  }
  acc.x += __shfl_xor(acc.x, 32, 64);
  acc.y += __shfl_xor(acc.y, 32, 64);
  acc.z += __shfl_xor(acc.z, 32, 64);
  acc.w += __shfl_xor(acc.w, 32, 64);
  if (lane < 32) *(float4*)&Y[(size_t)wave * 128 + l5 * 4] = acc;
}

// ---------------- attention pooling -> PT [128 f][NST nodes] ----------------

__device__ __forceinline__ float wave_sum(float v) {
#pragma unroll
  for (int d = 32; d > 0; d >>= 1) v += __shfl_xor(v, d, 64);
  return v;
}

__global__ __launch_bounds__(256) void pool_kernel(
    const float* __restrict__ R0f, const float* __restrict__ I0f,
    const float* __restrict__ X1, const float* __restrict__ X2,
    const float* __restrict__ X3, const float* __restrict__ rattw,
    const float* __restrict__ rattb, const float* __restrict__ iattw,
    const float* __restrict__ iattb, float* __restrict__ PT, int n) {
  __shared__ float pt[128 * 65];  // 33.3 KB, [f-row][node-col], stride 65
  int wid = threadIdx.x >> 6, lane = threadIdx.x & 63;
  int nb = blockIdx.x * 64;
  float aw = rattw[lane], bw = iattw[lane];
  float rb0 = rattb[0], ib0 = iattb[0];
  for (int k = 0; k < 16; ++k) {
    int ln = wid * 16 + k;
    int nc = min(nb + ln, n - 1);
    float r0 = R0f[(size_t)nc * 64 + lane];
    float q0 = I0f[(size_t)nc * 64 + lane];
    size_t base = (size_t)nc * 128 + 2 * lane;
    float2 v1 = *(const float2*)&X1[base];
    float2 v2 = *(const float2*)&X2[base];
    float2 v3 = *(const float2*)&X3[base];
    float ra0 = wave_sum(r0 * aw) + rb0;
    float ra1 = wave_sum(v1.x * aw) + rb0;
    float ra2 = wave_sum(v2.x * aw) + rb0;
    float ra3 = wave_sum(v3.x * aw) + rb0;
    float ia0 = wave_sum(q0 * bw) + ib0;
    float ia1 = wave_sum(v1.y * bw) + ib0;
    float ia2 = wave_sum(v2.y * bw) + ib0;
    float ia3 = wave_sum(v3.y * bw) + ib0;
    float s0 = 1.f / (1.f + __expf(-ra0));
    float s1 = 1.f / (1.f + __expf(-ra1));
    float s2 = 1.f / (1.f + __expf(-ra2));
    float s3 = 1.f / (1.f + __expf(-ra3));
    float t0 = 1.f / (1.f + __expf(-ia0));
    float t1 = 1.f / (1.f + __expf(-ia1));
    float t2 = 1.f / (1.f + __expf(-ia2));
    float t3 = 1.f / (1.f + __expf(-ia3));
    float mR = fmaxf(fmaxf(s0, s1), fmaxf(s2, s3));
    float e0 = __expf(s0 - mR), e1 = __expf(s1 - mR), e2 = __expf(s2 - mR),
          e3 = __expf(s3 - mR);
    float invR = 1.f / (e0 + e1 + e2 + e3);
    float mI = fmaxf(fmaxf(t0, t1), fmaxf(t2, t3));
    float g0 = __expf(t0 - mI), g1 = __expf(t1 - mI), g2 = __expf(t2 - mI),
          g3 = __expf(t3 - mI);
    float invI = 1.f / (g0 + g1 + g2 + g3);
    float pr = (r0 * e0 + v1.x * e1 + v2.x * e2 + v3.x * e3) * invR;
    float pi = (q0 * g0 + v1.y * g1 + v2.y * g2 + v3.y * g3) * invI;
    pt[lane * 65 + ln] = pr;
    pt[(64 + lane) * 65 + ln] = pi;
  }
  __syncthreads();
  int c = threadIdx.x & 63, fr = threadIdx.x >> 6;
  for (int r = 0; r < 32; ++r) {
    int f = fr * 32 + r;
    int nd = nb + c;
    if (nd < n) PT[(size_t)f * NST + nd] = pt[f * 65 + c];
  }
}

// ---------------- fused MLP: two-pass z-tile, 33.8 KB LDS ----------------
// Waves 0,1 produce layer-0 h in [0,64); all waves accumulate y over that
// half; waves 2,3 produce h in [64,128); accumulate second half. Layer-0 is
// computed in 16-h chunks so z (32 regs) + y (64 regs) stay under 128 VGPRs.

__global__ __launch_bounds__(256, 4) void mlp_kernel(
    const float* __restrict__ PT, const float* __restrict__ r0T,
    const float* __restrict__ r0b, const float* __restrict__ i0T,
    const float* __restrict__ i0b, const float* __restrict__ r1T,
    const float* __restrict__ r1b, const float* __restrict__ i1T,
    const float* __restrict__ i1b, const float* __restrict__ ow,
    const float* __restrict__ ob, float* __restrict__ out, int n) {
  __shared__ float buf[8448];  // 33 KB: z half-tile [128][65] / partials [4][64][33]
  int lane = threadIdx.x & 63;
  int wid = threadIdx.x >> 6;
  int h0 = __builtin_amdgcn_readfirstlane(wid * 32);
  int nb = blockIdx.x * 64;
  int node = min(nb + lane, n - 1);  // tail lanes recompute node n-1

  // layer-0 16-h chunk: h in [hb, hb+16); writes masked z to rows (h&63 | 64+(h&63))
  auto layer0_chunk = [&](int hb) {
    float zr[16], zi[16];
#pragma unroll
    for (int j = 0; j < 16; ++j) {
      zr[j] = r0b[hb + j];
      zi[j] = i0b[hb + j];
    }
#pragma unroll 4
    for (int f = 0; f < 64; ++f) {
      float ar = PT[(size_t)f * NST + node];
      float ai = PT[(size_t)(64 + f) * NST + node];
      const float* wr = &r0T[f * 128 + hb];
      const float* wi = &i0T[f * 128 + hb];
#pragma unroll
      for (int j = 0; j < 16; ++j) {
        zr[j] += ar * wr[j];
        zi[j] += ai * wi[j];
      }
    }
    int rbase = hb & 63;
#pragma unroll
    for (int j = 0; j < 16; ++j) {
      float m = (zr[j] >= 0.f) ? 1.f : 0.f;
      buf[(rbase + j) * 65 + lane] = zr[j] * m;
      buf[(64 + rbase + j) * 65 + lane] = zi[j] * m;
    }
  };

  // ---- pass A: waves 0,1 -> z for f' in [0,64) ----
  if (wid < 2) {
    layer0_chunk(h0);
    layer0_chunk(h0 + 16);
  }
  __syncthreads();

  float yr[32], yi[32];
#pragma unroll
  for (int j = 0; j < 32; ++j) {
    yr[j] = r1b[h0 + j];
    yi[j] = i1b[h0 + j];
  }
#pragma unroll 2
  for (int f = 0; f < 64; ++f) {
    float ar = buf[f * 65 + lane];
    float ai = buf[(64 + f) * 65 + lane];
    const float* wr = &r1T[f * 128 + h0];
    const float* wi = &i1T[f * 128 + h0];
#pragma unroll
    for (int j = 0; j < 32; ++j) {
      yr[j] += ar * wr[j];
      yi[j] += ai * wi[j];
    }
  }
  __syncthreads();

  // ---- pass B: waves 2,3 -> z for f' in [64,128) ----
  if (wid >= 2) {
    layer0_chunk(h0);
    layer0_chunk(h0 + 16);
  }
  __syncthreads();

#pragma unroll 2
  for (int f = 64; f < 128; ++f) {
    float ar = buf[(f - 64) * 65 + lane];
    float ai = buf[f * 65 + lane];
    const float* wr = &r1T[f * 128 + h0];
    const float* wi = &i1T[f * 128 + h0];
#pragma unroll
    for (int j = 0; j < 32; ++j) {
      yr[j] += ar * wr[j];
      yi[j] += ai * wi[j];
    }
  }
#pragma unroll
  for (int j = 0; j < 32; ++j) {
    float m = (yr[j] >= 0.f) ? 1.f : 0.f;
    yr[j] *= m;
    yi[j] *= m;
  }
  __syncthreads();  // all reads of z-tile done; reuse buf for partials

  // ---- output partials over this wave's 32 h (re+im) ----
  float* pz = &buf[wid * 2112];
#pragma unroll 4
  for (int o = 0; o < 32; ++o) {
    const float* wrow = &ow[o * 256 + h0];
    float t = 0.f;
#pragma unroll
    for (int j = 0; j < 32; ++j) t += yr[j] * wrow[j] + yi[j] * wrow[128 + j];
    pz[lane * 33 + o] = t;
  }
  __syncthreads();

  for (int idx = threadIdx.x; idx < 2048; idx += 256) {
    int ln = idx >> 5, o = idx & 31;
    float s = buf[ln * 33 + o] + buf[2112 + ln * 33 + o] +
              buf[4224 + ln * 33 + o] + buf[6336 + ln * 33 + o] + ob[o];
    int nd = nb + ln;
    if (nd < n) out[(size_t)nd * 32 + o] = s;
  }
}

// ---------------- launch ----------------

extern "C" void kernel_launch(void* const* d_in, const int* in_sizes, int n_in,
                              void* d_out, int out_size, void* d_ws,
                              size_t ws_size, hipStream_t stream) {
  const float* realf = (const float*)d_in[0];
  const float* imagf = (const float*)d_in[1];
  const float* ent = (const float*)d_in[2];
  const float* ccf = (const float*)d_in[3];
  const float* wsym = (const float*)d_in[4];
  const float* q = (const float*)d_in[5];
  const float* encw = (const float*)d_in[6];
  const float* encb = (const float*)d_in[7];
  const float* rattw = (const float*)d_in[8];
  const float* rattb = (const float*)d_in[9];
  const float* iattw = (const float*)d_in[10];
  const float* iattb = (const float*)d_in[11];
  const float* r0w = (const float*)d_in[12];
  const float* r0b = (const float*)d_in[13];
  const float* r1w = (const float*)d_in[14];
  const float* r1b = (const float*)d_in[15];
  const float* i0w = (const float*)d_in[16];
  const float* i0b = (const float*)d_in[17];
  const float* i1w = (const float*)d_in[18];
  const float* i1b = (const float*)d_in[19];
  const float* ow = (const float*)d_in[20];
  const float* ob = (const float*)d_in[21];
  const int* row = (const int*)d_in[22];
  const int* col = (const int*)d_in[23];
  float* out = (float*)d_out;

  char* p = (char*)d_ws;
  auto alloc = [&](size_t bytes) -> void* {
    void* r = (void*)p;
    p += (bytes + 255) & ~(size_t)255;
    return r;
  };
  int* cnt = (int*)alloc(N_NODES * sizeof(int));
  int* offs = (int*)alloc((N_NODES + 1) * sizeof(int));
  int* col_s = (int*)alloc(N_EDGES * sizeof(int));
  float2* ws2 = (float2*)alloc(N_EDGES * sizeof(float2));
  size_t NX = (size_t)N_NODES * 128 * sizeof(float);  // interleaved level
  float* X0 = (float*)alloc(NX);
  float* X1 = (float*)alloc(NX);
  float* X2 = (float*)alloc(NX);
  float* X3 = (float*)alloc(NX);
  float* PT = (float*)alloc((size_t)128 * NST * sizeof(float));
  float* r0T = (float*)alloc(64 * 128 * 4);
  float* i0T = (float*)alloc(64 * 128 * 4);
  float* r1T = (float*)alloc(128 * 128 * 4);
  float* i1T = (float*)alloc(128 * 128 * 4);

  hipMemsetAsync(cnt, 0, N_NODES * sizeof(int), stream);
  prep_weights<<<64, 256, 0, stream>>>(r0w, i0w, r1w, i1w, r0T, i0T, r1T, i1T);
  hist_kernel<<<(N_EDGES + 255) / 256, 256, 0, stream>>>(row, cnt, N_EDGES);
  prefix_kernel<<<1, 1024, 0, stream>>>(cnt, offs, N_NODES, N_EDGES);
  scatter_kernel<<<(N_EDGES + 255) / 256, 256, 0, stream>>>(
      row, col, ent, ccf, wsym, encw, encb, q, cnt, col_s, ws2, N_EDGES);
  pack_kernel<<<(N_NODES * 64 + 255) / 256, 256, 0, stream>>>(
      realf, imagf, (float2*)X0, N_NODES * 64);

  const int pgrid = (N_NODES + 3) / 4;  // 4 waves (nodes) per 256-thread block
  prop_kernel<<<pgrid, 256, 0, stream>>>(X0, X1, offs, col_s, ws2, N_NODES);
  prop_kernel<<<pgrid, 256, 0, stream>>>(X1, X2, offs, col_s, ws2, N_NODES);
  prop_kernel<<<pgrid, 256, 0, stream>>>(X2, X3, offs, col_s, ws2, N_NODES);

  const int hgrid = (N_NODES + 63) / 64;  // 64 nodes per 256-thread block
  pool_kernel<<<hgrid, 256, 0, stream>>>(realf, imagf, X1, X2, X3, rattw,
                                         rattb, iattw, iattb, PT, N_NODES);
  mlp_kernel<<<hgrid, 256, 0, stream>>>(PT, r0T, r0b, i0T, i0b, r1T, r1b, i1T,
                                        i1b, ow, ob, out, N_NODES);
}

// Round 5
// 525.937 us; speedup vs baseline: 1.2167x; 1.2167x over previous
//
#include <hip/hip_runtime.h>

#define N_NODES 50000
#define N_EDGES 800000
#define FDIM 64
#define NST 50000  // PT row stride (floats)

// ---------------- edge weight + CSR construction ----------------

__global__ __launch_bounds__(256) void hist_kernel(const int* __restrict__ row,
                                                   int* __restrict__ cnt, int E) {
  int e = blockIdx.x * 256 + threadIdx.x;
  if (e < E) atomicAdd(&cnt[row[e]], 1);
}

__global__ __launch_bounds__(1024) void prefix_kernel(int* __restrict__ cnt,
                                                      int* __restrict__ offs,
                                                      int n, int E) {
  __shared__ int tot[1024];
  int t = threadIdx.x;
  int CH = (n + 1023) >> 10;
  int b = t * CH;
  int e = min(b + CH, n);
  int s = 0;
  for (int i = b; i < e; ++i) s += cnt[i];
  tot[t] = s;
  __syncthreads();
  for (int d = 1; d < 1024; d <<= 1) {
    int add = (t >= d) ? tot[t - d] : 0;
    __syncthreads();
    tot[t] += add;
    __syncthreads();
  }
  int run = (t == 0) ? 0 : tot[t - 1];
  for (int i = b; i < e; ++i) {
    int h = cnt[i];
    offs[i] = run;
    cnt[i] = run;  // becomes the scatter cursor
    run += h;
  }
  if (t == 0) offs[n] = E;
}

__global__ __launch_bounds__(256) void scatter_kernel(
    const int* __restrict__ row, const int* __restrict__ col,
    const float* __restrict__ ent, const float* __restrict__ ccf,
    const float* __restrict__ wsym, const float* __restrict__ encw,
    const float* __restrict__ encb, const float* __restrict__ q,
    int* __restrict__ cursor, int* __restrict__ col_s,
    float2* __restrict__ ws, int E) {
  int e = blockIdx.x * 256 + threadIdx.x;
  if (e >= E) return;
  float se = encw[0] * ent[e] + encw[1] * ccf[e] + encb[0];
  float ph = q[0] * se;
  float sw, cw;
  sincosf(ph, &sw, &cw);
  float w = wsym[e];
  int pos = atomicAdd(&cursor[row[e]], 1);
  col_s[pos] = col[e];
  ws[pos] = make_float2(w * cw, w * sw);
}

// ---------------- weight transpose prep ----------------

__global__ __launch_bounds__(256) void prep_weights(
    const float* __restrict__ r0, const float* __restrict__ i0,
    const float* __restrict__ r1, const float* __restrict__ i1,
    float* __restrict__ r0T, float* __restrict__ i0T, float* __restrict__ r1T,
    float* __restrict__ i1T) {
  int t = blockIdx.x * 256 + threadIdx.x;
  if (t < 128 * 64) {  // [128 h][64 f] -> [64 f][128 h]
    int h = t / 64, f = t % 64;
    r0T[f * 128 + h] = r0[t];
    i0T[f * 128 + h] = i0[t];
  }
  if (t < 128 * 128) {  // [128 h][128 f] -> [128 f][128 h]
    int h = t / 128, f = t % 128;
    r1T[f * 128 + h] = r1[t];
    i1T[f * 128 + h] = i1[t];
  }
}

// ---------------- pack re/im into interleaved rows ----------------

__global__ __launch_bounds__(256) void pack_kernel(const float* __restrict__ re,
                                                   const float* __restrict__ im,
                                                   float2* __restrict__ X,
                                                   int total) {  // total = N*64
  int i = blockIdx.x * 256 + threadIdx.x;
  if (i < total) X[i] = make_float2(re[i], im[i]);
}

// ---------------- complex propagation: up to 8 edges in flight ----------------
// X rows are [re0,im0,re1,im1,...] (128 floats). Lane l: half = l>>5 picks
// edge j+2k+half; l&31 picks a float4 (2 features re+im). shfl_xor(32) combines.

__global__ __launch_bounds__(256) void prop_kernel(
    const float* __restrict__ X, float* __restrict__ Y,
    const int* __restrict__ offs, const int* __restrict__ col_s,
    const float2* __restrict__ ws, int n) {
  int wave = (int)((blockIdx.x * (size_t)blockDim.x + threadIdx.x) >> 6);
  int lane = threadIdx.x & 63;
  if (wave >= n) return;
  int half = lane >> 5, l5 = lane & 31;
  const float* Xl = X + l5 * 4;
  int beg = offs[wave], end = offs[wave + 1];
  float4 acc = make_float4(0.f, 0.f, 0.f, 0.f);
  int j = beg;
  for (; j + 8 <= end; j += 8) {
    int c0 = col_s[j + half];
    int c1 = col_s[j + 2 + half];
    int c2 = col_s[j + 4 + half];
    int c3 = col_s[j + 6 + half];
    float2 w0 = ws[j + half];
    float2 w1 = ws[j + 2 + half];
    float2 w2 = ws[j + 4 + half];
    float2 w3 = ws[j + 6 + half];
    float4 x0 = *(const float4*)&Xl[(size_t)c0 * 128];
    float4 x1 = *(const float4*)&Xl[(size_t)c1 * 128];
    float4 x2 = *(const float4*)&Xl[(size_t)c2 * 128];
    float4 x3 = *(const float4*)&Xl[(size_t)c3 * 128];
    acc.x += w0.x * x0.x - w0.y * x0.y;
    acc.y += w0.y * x0.x + w0.x * x0.y;
    acc.z += w0.x * x0.z - w0.y * x0.w;
    acc.w += w0.y * x0.z + w0.x * x0.w;
    acc.x += w1.x * x1.x - w1.y * x1.y;
    acc.y += w1.y * x1.x + w1.x * x1.y;
    acc.z += w1.x * x1.z - w1.y * x1.w;
    acc.w += w1.y * x1.z + w1.x * x1.w;
    acc.x += w2.x * x2.x - w2.y * x2.y;
    acc.y += w2.y * x2.x + w2.x * x2.y;
    acc.z += w2.x * x2.z - w2.y * x2.w;
    acc.w += w2.y * x2.z + w2.x * x2.w;
    acc.x += w3.x * x3.x - w3.y * x3.y;
    acc.y += w3.y * x3.x + w3.x * x3.y;
    acc.z += w3.x * x3.z - w3.y * x3.w;
    acc.w += w3.y * x3.z + w3.x * x3.w;
  }
  for (; j + 4 <= end; j += 4) {
    int c0 = col_s[j + half];
    int c1 = col_s[j + 2 + half];
    float2 w0 = ws[j + half];
    float2 w1 = ws[j + 2 + half];
    float4 x0 = *(const float4*)&Xl[(size_t)c0 * 128];
    float4 x1 = *(const float4*)&Xl[(size_t)c1 * 128];
    acc.x += w0.x * x0.x - w0.y * x0.y;
    acc.y += w0.y * x0.x + w0.x * x0.y;
    acc.z += w0.x * x0.z - w0.y * x0.w;
    acc.w += w0.y * x0.z + w0.x * x0.w;
    acc.x += w1.x * x1.x - w1.y * x1.y;
    acc.y += w1.y * x1.x + w1.x * x1.y;
    acc.z += w1.x * x1.z - w1.y * x1.w;
    acc.w += w1.y * x1.z + w1.x * x1.w;
  }
  for (; j < end; j += 2) {
    int je = j + half;
    bool valid = je < end;
    int jc = valid ? je : beg;
    float2 w = ws[jc];
    float wr = valid ? w.x : 0.f;
    float wi = valid ? w.y : 0.f;
    int cc = col_s[jc];
    float4 x = *(const float4*)&Xl[(size_t)cc * 128];
    acc.x += wr * x.x - wi * x.y;
    acc.y += wi * x.x + wr * x.y;
    acc.z += wr * x.z - wi * x.w;
    acc.w += wi * x.z + wr * x.w;
  }
  acc.x += __shfl_xor(acc.x, 32, 64);
  acc.y += __shfl_xor(acc.y, 32, 64);
  acc.z += __shfl_xor(acc.z, 32, 64);
  acc.w += __shfl_xor(acc.w, 32, 64);
  if (lane < 32) *(float4*)&Y[(size_t)wave * 128 + l5 * 4] = acc;
}

// ---------------- attention pooling -> PT [128 f][NST nodes] ----------------

__device__ __forceinline__ float wave_sum(float v) {
#pragma unroll
  for (int d = 32; d > 0; d >>= 1) v += __shfl_xor(v, d, 64);
  return v;
}

__global__ __launch_bounds__(256) void pool_kernel(
    const float* __restrict__ R0f, const float* __restrict__ I0f,
    const float* __restrict__ X1, const float* __restrict__ X2,
    const float* __restrict__ X3, const float* __restrict__ rattw,
    const float* __restrict__ rattb, const float* __restrict__ iattw,
    const float* __restrict__ iattb, float* __restrict__ PT, int n) {
  __shared__ float pt[128 * 65];  // 33.3 KB, [f-row][node-col], stride 65
  int wid = threadIdx.x >> 6, lane = threadIdx.x & 63;
  int nb = blockIdx.x * 64;
  float aw = rattw[lane], bw = iattw[lane];
  float rb0 = rattb[0], ib0 = iattb[0];
  for (int k = 0; k < 16; ++k) {
    int ln = wid * 16 + k;
    int nc = min(nb + ln, n - 1);
    float r0 = R0f[(size_t)nc * 64 + lane];
    float q0 = I0f[(size_t)nc * 64 + lane];
    size_t base = (size_t)nc * 128 + 2 * lane;
    float2 v1 = *(const float2*)&X1[base];
    float2 v2 = *(const float2*)&X2[base];
    float2 v3 = *(const float2*)&X3[base];
    float ra0 = wave_sum(r0 * aw) + rb0;
    float ra1 = wave_sum(v1.x * aw) + rb0;
    float ra2 = wave_sum(v2.x * aw) + rb0;
    float ra3 = wave_sum(v3.x * aw) + rb0;
    float ia0 = wave_sum(q0 * bw) + ib0;
    float ia1 = wave_sum(v1.y * bw) + ib0;
    float ia2 = wave_sum(v2.y * bw) + ib0;
    float ia3 = wave_sum(v3.y * bw) + ib0;
    float s0 = 1.f / (1.f + __expf(-ra0));
    float s1 = 1.f / (1.f + __expf(-ra1));
    float s2 = 1.f / (1.f + __expf(-ra2));
    float s3 = 1.f / (1.f + __expf(-ra3));
    float t0 = 1.f / (1.f + __expf(-ia0));
    float t1 = 1.f / (1.f + __expf(-ia1));
    float t2 = 1.f / (1.f + __expf(-ia2));
    float t3 = 1.f / (1.f + __expf(-ia3));
    float mR = fmaxf(fmaxf(s0, s1), fmaxf(s2, s3));
    float e0 = __expf(s0 - mR), e1 = __expf(s1 - mR), e2 = __expf(s2 - mR),
          e3 = __expf(s3 - mR);
    float invR = 1.f / (e0 + e1 + e2 + e3);
    float mI = fmaxf(fmaxf(t0, t1), fmaxf(t2, t3));
    float g0 = __expf(t0 - mI), g1 = __expf(t1 - mI), g2 = __expf(t2 - mI),
          g3 = __expf(t3 - mI);
    float invI = 1.f / (g0 + g1 + g2 + g3);
    float pr = (r0 * e0 + v1.x * e1 + v2.x * e2 + v3.x * e3) * invR;
    float pi = (q0 * g0 + v1.y * g1 + v2.y * g2 + v3.y * g3) * invI;
    pt[lane * 65 + ln] = pr;
    pt[(64 + lane) * 65 + ln] = pi;
  }
  __syncthreads();
  int c = threadIdx.x & 63, fr = threadIdx.x >> 6;
  for (int r = 0; r < 32; ++r) {
    int f = fr * 32 + r;
    int nd = nb + c;
    if (nd < n) PT[(size_t)f * NST + nd] = pt[f * 65 + c];
  }
}

// ---------------- fused MLP: re/im independent GEMMs through one 33 KB tile --
// 512 threads = 8 waves x 16 h. Re and im halves share one [128][65] LDS tile
// sequentially (they only couple via the ReLU mask, which is thread-local).
// Output layer is o-distributed: wave w computes outputs 4w..4w+3 from the
// staged masked-y tiles. Weights stream via s_load (wave-uniform addresses).

__global__ __launch_bounds__(512, 8) void mlp_kernel(
    const float* __restrict__ PT, const float* __restrict__ r0T,
    const float* __restrict__ r0b, const float* __restrict__ i0T,
    const float* __restrict__ i0b, const float* __restrict__ r1T,
    const float* __restrict__ r1b, const float* __restrict__ i1T,
    const float* __restrict__ i1b, const float* __restrict__ ow,
    const float* __restrict__ ob, float* __restrict__ out, int n) {
  __shared__ float zt[128 * 65];  // 33.3 KB
  int lane = threadIdx.x & 63;
  int wid = threadIdx.x >> 6;  // 0..7
  int h0 = __builtin_amdgcn_readfirstlane(wid * 16);
  int nb = blockIdx.x * 64;
  int node = min(nb + lane, n - 1);  // tail lanes duplicate node n-1 (benign)

  // ---- layer 0: zr,zi for h in [h0,h0+16) ----
  float zr[16], zi[16];
#pragma unroll
  for (int j = 0; j < 16; ++j) {
    zr[j] = r0b[h0 + j];
    zi[j] = i0b[h0 + j];
  }
#pragma unroll 2
  for (int f = 0; f < 64; ++f) {
    float ar = PT[(size_t)f * NST + node];
    float ai = PT[(size_t)(64 + f) * NST + node];
    const float* wr = &r0T[f * 128 + h0];
    const float* wi = &i0T[f * 128 + h0];
#pragma unroll
    for (int j = 0; j < 16; ++j) {
      zr[j] += ar * wr[j];
      zi[j] += ai * wi[j];
    }
  }
#pragma unroll
  for (int j = 0; j < 16; ++j) {
    float m = (zr[j] >= 0.f) ? 1.f : 0.f;
    zr[j] *= m;
    zi[j] *= m;
  }

  // ---- layer 1, re pass ----
#pragma unroll
  for (int j = 0; j < 16; ++j) zt[(h0 + j) * 65 + lane] = zr[j];
  __syncthreads();
  float yr[16];
#pragma unroll
  for (int j = 0; j < 16; ++j) yr[j] = r1b[h0 + j];
#pragma unroll 2
  for (int f = 0; f < 128; ++f) {
    float a = zt[f * 65 + lane];
    const float* w = &r1T[f * 128 + h0];
#pragma unroll
    for (int j = 0; j < 16; ++j) yr[j] += a * w[j];
  }
  __syncthreads();

  // ---- layer 1, im pass ----
#pragma unroll
  for (int j = 0; j < 16; ++j) zt[(h0 + j) * 65 + lane] = zi[j];
  __syncthreads();
  float yi[16];
#pragma unroll
  for (int j = 0; j < 16; ++j) yi[j] = i1b[h0 + j];
#pragma unroll 2
  for (int f = 0; f < 128; ++f) {
    float a = zt[f * 65 + lane];
    const float* w = &i1T[f * 128 + h0];
#pragma unroll
    for (int j = 0; j < 16; ++j) yi[j] += a * w[j];
  }
#pragma unroll
  for (int j = 0; j < 16; ++j) {
    float m = (yr[j] >= 0.f) ? 1.f : 0.f;
    yr[j] *= m;
    yi[j] *= m;
  }
  __syncthreads();

  // ---- output layer: wave w owns o = 4w..4w+3 ----
  int o0 = __builtin_amdgcn_readfirstlane(wid * 4);
  float os[4] = {0.f, 0.f, 0.f, 0.f};
#pragma unroll
  for (int j = 0; j < 16; ++j) zt[(h0 + j) * 65 + lane] = yr[j];
  __syncthreads();
#pragma unroll 2
  for (int h = 0; h < 128; ++h) {
    float v = zt[h * 65 + lane];
    const float* w = &ow[o0 * 256 + h];
#pragma unroll
    for (int oo = 0; oo < 4; ++oo) os[oo] += v * w[oo * 256];
  }
  __syncthreads();
#pragma unroll
  for (int j = 0; j < 16; ++j) zt[(h0 + j) * 65 + lane] = yi[j];
  __syncthreads();
#pragma unroll 2
  for (int h = 0; h < 128; ++h) {
    float v = zt[h * 65 + lane];
    const float* w = &ow[o0 * 256 + 128 + h];
#pragma unroll
    for (int oo = 0; oo < 4; ++oo) os[oo] += v * w[oo * 256];
  }
#pragma unroll
  for (int oo = 0; oo < 4; ++oo)
    out[(size_t)node * 32 + o0 + oo] = os[oo] + ob[o0 + oo];
}

// ---------------- launch ----------------

extern "C" void kernel_launch(void* const* d_in, const int* in_sizes, int n_in,
                              void* d_out, int out_size, void* d_ws,
                              size_t ws_size, hipStream_t stream) {
  const float* realf = (const float*)d_in[0];
  const float* imagf = (const float*)d_in[1];
  const float* ent = (const float*)d_in[2];
  const float* ccf = (const float*)d_in[3];
  const float* wsym = (const float*)d_in[4];
  const float* q = (const float*)d_in[5];
  const float* encw = (const float*)d_in[6];
  const float* encb = (const float*)d_in[7];
  const float* rattw = (const float*)d_in[8];
  const float* rattb = (const float*)d_in[9];
  const float* iattw = (const float*)d_in[10];
  const float* iattb = (const float*)d_in[11];
  const float* r0w = (const float*)d_in[12];
  const float* r0b = (const float*)d_in[13];
  const float* r1w = (const float*)d_in[14];
  const float* r1b = (const float*)d_in[15];
  const float* i0w = (const float*)d_in[16];
  const float* i0b = (const float*)d_in[17];
  const float* i1w = (const float*)d_in[18];
  const float* i1b = (const float*)d_in[19];
  const float* ow = (const float*)d_in[20];
  const float* ob = (const float*)d_in[21];
  const int* row = (const int*)d_in[22];
  const int* col = (const int*)d_in[23];
  float* out = (float*)d_out;

  char* p = (char*)d_ws;
  auto alloc = [&](size_t bytes) -> void* {
    void* r = (void*)p;
    p += (bytes + 255) & ~(size_t)255;
    return r;
  };
  int* cnt = (int*)alloc(N_NODES * sizeof(int));
  int* offs = (int*)alloc((N_NODES + 1) * sizeof(int));
  int* col_s = (int*)alloc(N_EDGES * sizeof(int));
  float2* ws2 = (float2*)alloc(N_EDGES * sizeof(float2));
  size_t NX = (size_t)N_NODES * 128 * sizeof(float);  // interleaved level
  float* X0 = (float*)alloc(NX);
  float* X1 = (float*)alloc(NX);
  float* X2 = (float*)alloc(NX);
  float* X3 = (float*)alloc(NX);
  float* PT = (float*)alloc((size_t)128 * NST * sizeof(float));
  float* r0T = (float*)alloc(64 * 128 * 4);
  float* i0T = (float*)alloc(64 * 128 * 4);
  float* r1T = (float*)alloc(128 * 128 * 4);
  float* i1T = (float*)alloc(128 * 128 * 4);

  hipMemsetAsync(cnt, 0, N_NODES * sizeof(int), stream);
  prep_weights<<<64, 256, 0, stream>>>(r0w, i0w, r1w, i1w, r0T, i0T, r1T, i1T);
  hist_kernel<<<(N_EDGES + 255) / 256, 256, 0, stream>>>(row, cnt, N_EDGES);
  prefix_kernel<<<1, 1024, 0, stream>>>(cnt, offs, N_NODES, N_EDGES);
  scatter_kernel<<<(N_EDGES + 255) / 256, 256, 0, stream>>>(
      row, col, ent, ccf, wsym, encw, encb, q, cnt, col_s, ws2, N_EDGES);
  pack_kernel<<<(N_NODES * 64 + 255) / 256, 256, 0, stream>>>(
      realf, imagf, (float2*)X0, N_NODES * 64);

  const int pgrid = (N_NODES + 3) / 4;  // 4 waves (nodes) per 256-thread block
  prop_kernel<<<pgrid, 256, 0, stream>>>(X0, X1, offs, col_s, ws2, N_NODES);
  prop_kernel<<<pgrid, 256, 0, stream>>>(X1, X2, offs, col_s, ws2, N_NODES);
  prop_kernel<<<pgrid, 256, 0, stream>>>(X2, X3, offs, col_s, ws2, N_NODES);

  const int hgrid = (N_NODES + 63) / 64;  // 64 nodes per block
  pool_kernel<<<hgrid, 256, 0, stream>>>(realf, imagf, X1, X2, X3, rattw,
                                         rattb, iattw, iattb, PT, N_NODES);
  mlp_kernel<<<hgrid, 512, 0, stream>>>(PT, r0T, r0b, i0T, i0b, r1T, r1b, i1T,
                                        i1b, ow, ob, out, N_NODES);
}

// Round 6
// 423.665 us; speedup vs baseline: 1.5104x; 1.2414x over previous
//
#include <hip/hip_runtime.h>

#define N_NODES 50000
#define N_EDGES 800000
#define FDIM 64
#define NST 50000   // PT row stride (floats)
#define SA_BLOCKS ((N_NODES + 1023) / 1024)

// ---------------- edge weight + CSR construction ----------------

__global__ __launch_bounds__(256) void hist_kernel(const int* __restrict__ row,
                                                   int* __restrict__ cnt, int E) {
  int e = blockIdx.x * 256 + threadIdx.x;
  if (e < E) atomicAdd(&cnt[row[e]], 1);
}

// hierarchical scan: A) per-1024 block scan, B) scan block sums, C) apply
__global__ __launch_bounds__(1024) void scanA_kernel(const int* __restrict__ cnt,
                                                     int* __restrict__ offs,
                                                     int* __restrict__ bsum,
                                                     int n) {
  __shared__ int s[1024];
  int t = threadIdx.x;
  int i = blockIdx.x * 1024 + t;
  int v = (i < n) ? cnt[i] : 0;
  s[t] = v;
  __syncthreads();
  for (int d = 1; d < 1024; d <<= 1) {
    int add = (t >= d) ? s[t - d] : 0;
    __syncthreads();
    s[t] += add;
    __syncthreads();
  }
  if (i < n) offs[i] = s[t] - v;  // local exclusive
  if (t == 1023) bsum[blockIdx.x] = s[1023];
}

__global__ __launch_bounds__(64) void scanB_kernel(int* __restrict__ bsum,
                                                   int* __restrict__ boff,
                                                   int nb) {
  __shared__ int s[64];
  int t = threadIdx.x;
  int v = (t < nb) ? bsum[t] : 0;
  s[t] = v;
  __syncthreads();
  for (int d = 1; d < 64; d <<= 1) {
    int add = (t >= d) ? s[t - d] : 0;
    __syncthreads();
    s[t] += add;
    __syncthreads();
  }
  if (t < nb) boff[t] = s[t] - v;  // exclusive
}

__global__ __launch_bounds__(1024) void scanC_kernel(int* __restrict__ offs,
                                                     int* __restrict__ cursor,
                                                     const int* __restrict__ boff,
                                                     int n, int E) {
  int t = threadIdx.x;
  int i = blockIdx.x * 1024 + t;
  int bo = boff[blockIdx.x];
  if (i < n) {
    int o = offs[i] + bo;
    offs[i] = o;
    cursor[i] = o;
  }
  if (i == 0) offs[n] = E;
}

__global__ __launch_bounds__(256) void scatter_kernel(
    const int* __restrict__ row, const int* __restrict__ col,
    const float* __restrict__ ent, const float* __restrict__ ccf,
    const float* __restrict__ wsym, const float* __restrict__ encw,
    const float* __restrict__ encb, const float* __restrict__ q,
    int* __restrict__ cursor, int* __restrict__ col_s,
    float2* __restrict__ ws, int E) {
  int e = blockIdx.x * 256 + threadIdx.x;
  if (e >= E) return;
  float se = encw[0] * ent[e] + encw[1] * ccf[e] + encb[0];
  float ph = q[0] * se;
  float sw, cw;
  sincosf(ph, &sw, &cw);
  float w = wsym[e];
  int pos = atomicAdd(&cursor[row[e]], 1);
  col_s[pos] = col[e];
  ws[pos] = make_float2(w * cw, w * sw);
}

// ---------------- weight transpose prep ----------------

__global__ __launch_bounds__(256) void prep_weights(
    const float* __restrict__ r0, const float* __restrict__ i0,
    const float* __restrict__ r1, const float* __restrict__ i1,
    float* __restrict__ r0T, float* __restrict__ i0T, float* __restrict__ r1T,
    float* __restrict__ i1T) {
  int t = blockIdx.x * 256 + threadIdx.x;
  if (t < 128 * 64) {  // [128 h][64 f] -> [64 f][128 h]
    int h = t / 64, f = t % 64;
    r0T[f * 128 + h] = r0[t];
    i0T[f * 128 + h] = i0[t];
  }
  if (t < 128 * 128) {  // [128 h][128 f] -> [128 f][128 h]
    int h = t / 128, f = t % 128;
    r1T[f * 128 + h] = r1[t];
    i1T[f * 128 + h] = i1[t];
  }
}

// ---------------- pack re/im into interleaved rows ----------------

__global__ __launch_bounds__(256) void pack_kernel(const float* __restrict__ re,
                                                   const float* __restrict__ im,
                                                   float2* __restrict__ X,
                                                   int total) {  // total = N*64
  int i = blockIdx.x * 256 + threadIdx.x;
  if (i < total) X[i] = make_float2(re[i], im[i]);
}

// ---------------- complex propagation: up to 16 edges in flight ----------------
// X rows are [re0,im0,re1,im1,...] (128 floats). Lane l: half = l>>5 picks
// edge j+2k+half; l&31 picks a float4 (2 features re+im). shfl_xor(32) combines.

__global__ __launch_bounds__(256) void prop_kernel(
    const float* __restrict__ X, float* __restrict__ Y,
    const int* __restrict__ offs, const int* __restrict__ col_s,
    const float2* __restrict__ ws, int n) {
  int wave = (int)((blockIdx.x * (size_t)blockDim.x + threadIdx.x) >> 6);
  int lane = threadIdx.x & 63;
  if (wave >= n) return;
  int half = lane >> 5, l5 = lane & 31;
  const float* Xl = X + l5 * 4;
  int beg = offs[wave], end = offs[wave + 1];
  float4 acc = make_float4(0.f, 0.f, 0.f, 0.f);
  int j = beg;
  for (; j + 16 <= end; j += 16) {
    int c[8];
    float2 w[8];
    float4 x[8];
#pragma unroll
    for (int k = 0; k < 8; ++k) c[k] = col_s[j + 2 * k + half];
#pragma unroll
    for (int k = 0; k < 8; ++k) w[k] = ws[j + 2 * k + half];
#pragma unroll
    for (int k = 0; k < 8; ++k) x[k] = *(const float4*)&Xl[(size_t)c[k] * 128];
#pragma unroll
    for (int k = 0; k < 8; ++k) {
      acc.x += w[k].x * x[k].x - w[k].y * x[k].y;
      acc.y += w[k].y * x[k].x + w[k].x * x[k].y;
      acc.z += w[k].x * x[k].z - w[k].y * x[k].w;
      acc.w += w[k].y * x[k].z + w[k].x * x[k].w;
    }
  }
  for (; j + 8 <= end; j += 8) {
    int c[4];
    float2 w[4];
    float4 x[4];
#pragma unroll
    for (int k = 0; k < 4; ++k) c[k] = col_s[j + 2 * k + half];
#pragma unroll
    for (int k = 0; k < 4; ++k) w[k] = ws[j + 2 * k + half];
#pragma unroll
    for (int k = 0; k < 4; ++k) x[k] = *(const float4*)&Xl[(size_t)c[k] * 128];
#pragma unroll
    for (int k = 0; k < 4; ++k) {
      acc.x += w[k].x * x[k].x - w[k].y * x[k].y;
      acc.y += w[k].y * x[k].x + w[k].x * x[k].y;
      acc.z += w[k].x * x[k].z - w[k].y * x[k].w;
      acc.w += w[k].y * x[k].z + w[k].x * x[k].w;
    }
  }
  for (; j + 4 <= end; j += 4) {
    int c0 = col_s[j + half];
    int c1 = col_s[j + 2 + half];
    float2 w0 = ws[j + half];
    float2 w1 = ws[j + 2 + half];
    float4 x0 = *(const float4*)&Xl[(size_t)c0 * 128];
    float4 x1 = *(const float4*)&Xl[(size_t)c1 * 128];
    acc.x += w0.x * x0.x - w0.y * x0.y;
    acc.y += w0.y * x0.x + w0.x * x0.y;
    acc.z += w0.x * x0.z - w0.y * x0.w;
    acc.w += w0.y * x0.z + w0.x * x0.w;
    acc.x += w1.x * x1.x - w1.y * x1.y;
    acc.y += w1.y * x1.x + w1.x * x1.y;
    acc.z += w1.x * x1.z - w1.y * x1.w;
    acc.w += w1.y * x1.z + w1.x * x1.w;
  }
  for (; j < end; j += 2) {
    int je = j + half;
    bool valid = je < end;
    int jc = valid ? je : beg;
    float2 w = ws[jc];
    float wr = valid ? w.x : 0.f;
    float wi = valid ? w.y : 0.f;
    int cc = col_s[jc];
    float4 x = *(const float4*)&Xl[(size_t)cc * 128];
    acc.x += wr * x.x - wi * x.y;
    acc.y += wi * x.x + wr * x.y;
    acc.z += wr * x.z - wi * x.w;
    acc.w += wi * x.z + wr * x.w;
  }
  acc.x += __shfl_xor(acc.x, 32, 64);
  acc.y += __shfl_xor(acc.y, 32, 64);
  acc.z += __shfl_xor(acc.z, 32, 64);
  acc.w += __shfl_xor(acc.w, 32, 64);
  if (lane < 32) *(float4*)&Y[(size_t)wave * 128 + l5 * 4] = acc;
}

// ---------------- attention pooling -> PT [128 f][NST nodes] ----------------

__device__ __forceinline__ float wave_sum(float v) {
#pragma unroll
  for (int d = 32; d > 0; d >>= 1) v += __shfl_xor(v, d, 64);
  return v;
}

__global__ __launch_bounds__(256) void pool_kernel(
    const float* __restrict__ R0f, const float* __restrict__ I0f,
    const float* __restrict__ X1, const float* __restrict__ X2,
    const float* __restrict__ X3, const float* __restrict__ rattw,
    const float* __restrict__ rattb, const float* __restrict__ iattw,
    const float* __restrict__ iattb, float* __restrict__ PT, int n) {
  __shared__ float pt[128 * 65];  // 33.3 KB, [f-row][node-col], stride 65
  int wid = threadIdx.x >> 6, lane = threadIdx.x & 63;
  int nb = blockIdx.x * 64;
  float aw = rattw[lane], bw = iattw[lane];
  float rb0 = rattb[0], ib0 = iattb[0];
  for (int k = 0; k < 16; ++k) {
    int ln = wid * 16 + k;
    int nc = min(nb + ln, n - 1);
    float r0 = R0f[(size_t)nc * 64 + lane];
    float q0 = I0f[(size_t)nc * 64 + lane];
    size_t base = (size_t)nc * 128 + 2 * lane;
    float2 v1 = *(const float2*)&X1[base];
    float2 v2 = *(const float2*)&X2[base];
    float2 v3 = *(const float2*)&X3[base];
    float ra0 = wave_sum(r0 * aw) + rb0;
    float ra1 = wave_sum(v1.x * aw) + rb0;
    float ra2 = wave_sum(v2.x * aw) + rb0;
    float ra3 = wave_sum(v3.x * aw) + rb0;
    float ia0 = wave_sum(q0 * bw) + ib0;
    float ia1 = wave_sum(v1.y * bw) + ib0;
    float ia2 = wave_sum(v2.y * bw) + ib0;
    float ia3 = wave_sum(v3.y * bw) + ib0;
    float s0 = 1.f / (1.f + __expf(-ra0));
    float s1 = 1.f / (1.f + __expf(-ra1));
    float s2 = 1.f / (1.f + __expf(-ra2));
    float s3 = 1.f / (1.f + __expf(-ra3));
    float t0 = 1.f / (1.f + __expf(-ia0));
    float t1 = 1.f / (1.f + __expf(-ia1));
    float t2 = 1.f / (1.f + __expf(-ia2));
    float t3 = 1.f / (1.f + __expf(-ia3));
    float mR = fmaxf(fmaxf(s0, s1), fmaxf(s2, s3));
    float e0 = __expf(s0 - mR), e1 = __expf(s1 - mR), e2 = __expf(s2 - mR),
          e3 = __expf(s3 - mR);
    float invR = 1.f / (e0 + e1 + e2 + e3);
    float mI = fmaxf(fmaxf(t0, t1), fmaxf(t2, t3));
    float g0 = __expf(t0 - mI), g1 = __expf(t1 - mI), g2 = __expf(t2 - mI),
          g3 = __expf(t3 - mI);
    float invI = 1.f / (g0 + g1 + g2 + g3);
    float pr = (r0 * e0 + v1.x * e1 + v2.x * e2 + v3.x * e3) * invR;
    float pi = (q0 * g0 + v1.y * g1 + v2.y * g2 + v3.y * g3) * invI;
    pt[lane * 65 + ln] = pr;
    pt[(64 + lane) * 65 + ln] = pi;
  }
  __syncthreads();
  int c = threadIdx.x & 63, fr = threadIdx.x >> 6;
  for (int r = 0; r < 32; ++r) {
    int f = fr * 32 + r;
    int nd = nb + c;
    if (nd < n) PT[(size_t)f * NST + nd] = pt[f * 65 + c];
  }
}

// ---------------- fused MLP: re/im independent GEMMs through one 33 KB tile --

__global__ __launch_bounds__(512, 8) void mlp_kernel(
    const float* __restrict__ PT, const float* __restrict__ r0T,
    const float* __restrict__ r0b, const float* __restrict__ i0T,
    const float* __restrict__ i0b, const float* __restrict__ r1T,
    const float* __restrict__ r1b, const float* __restrict__ i1T,
    const float* __restrict__ i1b, const float* __restrict__ ow,
    const float* __restrict__ ob, float* __restrict__ out, int n) {
  __shared__ float zt[128 * 65];  // 33.3 KB
  int lane = threadIdx.x & 63;
  int wid = threadIdx.x >> 6;  // 0..7
  int h0 = __builtin_amdgcn_readfirstlane(wid * 16);
  int nb = blockIdx.x * 64;
  int node = min(nb + lane, n - 1);  // tail lanes duplicate node n-1 (benign)

  // ---- layer 0: zr,zi for h in [h0,h0+16) ----
  float zr[16], zi[16];
#pragma unroll
  for (int j = 0; j < 16; ++j) {
    zr[j] = r0b[h0 + j];
    zi[j] = i0b[h0 + j];
  }
#pragma unroll 2
  for (int f = 0; f < 64; ++f) {
    float ar = PT[(size_t)f * NST + node];
    float ai = PT[(size_t)(64 + f) * NST + node];
    const float* wr = &r0T[f * 128 + h0];
    const float* wi = &i0T[f * 128 + h0];
#pragma unroll
    for (int j = 0; j < 16; ++j) {
      zr[j] += ar * wr[j];
      zi[j] += ai * wi[j];
    }
  }
#pragma unroll
  for (int j = 0; j < 16; ++j) {
    float m = (zr[j] >= 0.f) ? 1.f : 0.f;
    zr[j] *= m;
    zi[j] *= m;
  }

  // ---- layer 1, re pass ----
#pragma unroll
  for (int j = 0; j < 16; ++j) zt[(h0 + j) * 65 + lane] = zr[j];
  __syncthreads();
  float yr[16];
#pragma unroll
  for (int j = 0; j < 16; ++j) yr[j] = r1b[h0 + j];
#pragma unroll 2
  for (int f = 0; f < 128; ++f) {
    float a = zt[f * 65 + lane];
    const float* w = &r1T[f * 128 + h0];
#pragma unroll
    for (int j = 0; j < 16; ++j) yr[j] += a * w[j];
  }
  __syncthreads();

  // ---- layer 1, im pass ----
#pragma unroll
  for (int j = 0; j < 16; ++j) zt[(h0 + j) * 65 + lane] = zi[j];
  __syncthreads();
  float yi[16];
#pragma unroll
  for (int j = 0; j < 16; ++j) yi[j] = i1b[h0 + j];
#pragma unroll 2
  for (int f = 0; f < 128; ++f) {
    float a = zt[f * 65 + lane];
    const float* w = &i1T[f * 128 + h0];
#pragma unroll
    for (int j = 0; j < 16; ++j) yi[j] += a * w[j];
  }
#pragma unroll
  for (int j = 0; j < 16; ++j) {
    float m = (yr[j] >= 0.f) ? 1.f : 0.f;
    yr[j] *= m;
    yi[j] *= m;
  }
  __syncthreads();

  // ---- output layer: wave w owns o = 4w..4w+3 ----
  int o0 = __builtin_amdgcn_readfirstlane(wid * 4);
  float os[4] = {0.f, 0.f, 0.f, 0.f};
#pragma unroll
  for (int j = 0; j < 16; ++j) zt[(h0 + j) * 65 + lane] = yr[j];
  __syncthreads();
#pragma unroll 2
  for (int h = 0; h < 128; ++h) {
    float v = zt[h * 65 + lane];
    const float* w = &ow[o0 * 256 + h];
#pragma unroll
    for (int oo = 0; oo < 4; ++oo) os[oo] += v * w[oo * 256];
  }
  __syncthreads();
#pragma unroll
  for (int j = 0; j < 16; ++j) zt[(h0 + j) * 65 + lane] = yi[j];
  __syncthreads();
#pragma unroll 2
  for (int h = 0; h < 128; ++h) {
    float v = zt[h * 65 + lane];
    const float* w = &ow[o0 * 256 + 128 + h];
#pragma unroll
    for (int oo = 0; oo < 4; ++oo) os[oo] += v * w[oo * 256];
  }
#pragma unroll
  for (int oo = 0; oo < 4; ++oo)
    out[(size_t)node * 32 + o0 + oo] = os[oo] + ob[o0 + oo];
}

// ---------------- launch ----------------

extern "C" void kernel_launch(void* const* d_in, const int* in_sizes, int n_in,
                              void* d_out, int out_size, void* d_ws,
                              size_t ws_size, hipStream_t stream) {
  const float* realf = (const float*)d_in[0];
  const float* imagf = (const float*)d_in[1];
  const float* ent = (const float*)d_in[2];
  const float* ccf = (const float*)d_in[3];
  const float* wsym = (const float*)d_in[4];
  const float* q = (const float*)d_in[5];
  const float* encw = (const float*)d_in[6];
  const float* encb = (const float*)d_in[7];
  const float* rattw = (const float*)d_in[8];
  const float* rattb = (const float*)d_in[9];
  const float* iattw = (const float*)d_in[10];
  const float* iattb = (const float*)d_in[11];
  const float* r0w = (const float*)d_in[12];
  const float* r0b = (const float*)d_in[13];
  const float* r1w = (const float*)d_in[14];
  const float* r1b = (const float*)d_in[15];
  const float* i0w = (const float*)d_in[16];
  const float* i0b = (const float*)d_in[17];
  const float* i1w = (const float*)d_in[18];
  const float* i1b = (const float*)d_in[19];
  const float* ow = (const float*)d_in[20];
  const float* ob = (const float*)d_in[21];
  const int* row = (const int*)d_in[22];
  const int* col = (const int*)d_in[23];
  float* out = (float*)d_out;

  char* p = (char*)d_ws;
  auto alloc = [&](size_t bytes) -> void* {
    void* r = (void*)p;
    p += (bytes + 255) & ~(size_t)255;
    return r;
  };
  int* cnt = (int*)alloc(N_NODES * sizeof(int));
  int* offs = (int*)alloc((N_NODES + 1) * sizeof(int));
  int* bsum = (int*)alloc(SA_BLOCKS * sizeof(int));
  int* boff = (int*)alloc(SA_BLOCKS * sizeof(int));
  int* col_s = (int*)alloc(N_EDGES * sizeof(int));
  float2* ws2 = (float2*)alloc(N_EDGES * sizeof(float2));
  size_t NX = (size_t)N_NODES * 128 * sizeof(float);  // interleaved level
  float* X0 = (float*)alloc(NX);
  float* X1 = (float*)alloc(NX);
  float* X2 = (float*)alloc(NX);
  float* X3 = (float*)alloc(NX);
  float* PT = (float*)alloc((size_t)128 * NST * sizeof(float));
  float* r0T = (float*)alloc(64 * 128 * 4);
  float* i0T = (float*)alloc(64 * 128 * 4);
  float* r1T = (float*)alloc(128 * 128 * 4);
  float* i1T = (float*)alloc(128 * 128 * 4);

  hipMemsetAsync(cnt, 0, N_NODES * sizeof(int), stream);
  prep_weights<<<64, 256, 0, stream>>>(r0w, i0w, r1w, i1w, r0T, i0T, r1T, i1T);
  hist_kernel<<<(N_EDGES + 255) / 256, 256, 0, stream>>>(row, cnt, N_EDGES);
  scanA_kernel<<<SA_BLOCKS, 1024, 0, stream>>>(cnt, offs, bsum, N_NODES);
  scanB_kernel<<<1, 64, 0, stream>>>(bsum, boff, SA_BLOCKS);
  scanC_kernel<<<SA_BLOCKS, 1024, 0, stream>>>(offs, cnt, boff, N_NODES,
                                               N_EDGES);
  scatter_kernel<<<(N_EDGES + 255) / 256, 256, 0, stream>>>(
      row, col, ent, ccf, wsym, encw, encb, q, cnt, col_s, ws2, N_EDGES);
  pack_kernel<<<(N_NODES * 64 + 255) / 256, 256, 0, stream>>>(
      realf, imagf, (float2*)X0, N_NODES * 64);

  const int pgrid = (N_NODES + 3) / 4;  // 4 waves (nodes) per 256-thread block
  prop_kernel<<<pgrid, 256, 0, stream>>>(X0, X1, offs, col_s, ws2, N_NODES);
  prop_kernel<<<pgrid, 256, 0, stream>>>(X1, X2, offs, col_s, ws2, N_NODES);
  prop_kernel<<<pgrid, 256, 0, stream>>>(X2, X3, offs, col_s, ws2, N_NODES);

  const int hgrid = (N_NODES + 63) / 64;  // 64 nodes per block
  pool_kernel<<<hgrid, 256, 0, stream>>>(realf, imagf, X1, X2, X3, rattw,
                                         rattb, iattw, iattb, PT, N_NODES);
  mlp_kernel<<<hgrid, 512, 0, stream>>>(PT, r0T, r0b, i0T, i0b, r1T, r1b, i1T,
                                        i1b, ow, ob, out, N_NODES);
}